// Round 3
// baseline (74.595 us; speedup 1.0000x reference)
//
#include <hip/hip_runtime.h>

#define TPB 256
#define NBLK 512

// Per-sample accumulation. KC>0: compile-time K (arrays in registers, fully
// unrolled — the bench's K=8 path). KC==0: generic runtime-K fallback reading
// indices/pos-scores straight from global (uniform, cache-hit) each time.
// All idx / pos-score addresses are blockIdx-derived (wave-uniform) -> the
// compiler emits scalar loads; no LDS, no __syncthreads in this loop.
template <int KC>
__device__ inline void accum_samples(const float* __restrict__ scores,
                                     const int* __restrict__ idx,
                                     int D, int B, int K,
                                     float& loss, float& pairs) {
    const int KK = (KC > 0) ? KC : K;
    for (int b = blockIdx.x; b < B; b += gridDim.x) {
        const int rbase = b * D;
        const int ibase = b * K;

        if (KC > 0) {
            int   ik[KC > 0 ? KC : 1];
            float ps[KC > 0 ? KC : 1];
            int   validmask = 0, P = 0;
#pragma unroll
            for (int k = 0; k < KC; ++k) ik[k] = idx[ibase + k];
#pragma unroll
            for (int k = 0; k < KC; ++k) {
                bool dup = false;
#pragma unroll
                for (int j = 0; j < KC; ++j)
                    if (j < k) dup |= (ik[j] == ik[k]);
                if (!dup) { validmask |= (1 << k); ++P; }
                ps[k] = scores[rbase + ik[k]];
            }
            for (int d = threadIdx.x; d < D; d += TPB) {
                const float s = scores[rbase + d] + 1.0f;  // margin folded in
                bool is_pos = false;
#pragma unroll
                for (int k = 0; k < KC; ++k) is_pos |= (ik[k] == d);
                if (!is_pos) {
#pragma unroll
                    for (int k = 0; k < KC; ++k) {
                        if (validmask & (1 << k)) {
                            float v = s - ps[k];
                            loss += (v > 0.0f) ? v : 0.0f;
                        }
                    }
                }
            }
            if (threadIdx.x == 0) pairs += (float)((D - P) * P);
        } else {
            // Generic fallback (not exercised by the bench shape).
            int P = 0;
            for (int k = 0; k < KK; ++k) {
                bool dup = false;
                for (int j = 0; j < k; ++j) dup |= (idx[ibase + j] == idx[ibase + k]);
                if (!dup) ++P;
            }
            for (int d = threadIdx.x; d < D; d += TPB) {
                const float s = scores[rbase + d] + 1.0f;
                bool is_pos = false;
                for (int k = 0; k < KK; ++k) is_pos |= (idx[ibase + k] == d);
                if (!is_pos) {
                    for (int k = 0; k < KK; ++k) {
                        bool dup = false;
                        for (int j = 0; j < k; ++j) dup |= (idx[ibase + j] == idx[ibase + k]);
                        if (!dup) {
                            float v = s - scores[rbase + idx[ibase + k]];
                            loss += (v > 0.0f) ? v : 0.0f;
                        }
                    }
                }
            }
            if (threadIdx.x == 0) pairs += (float)((D - P) * P);
        }
    }
}

// ws layout: [0..3] uint counter (memset 0 by kernel_launch); [16..] float2 partials.
__global__ __launch_bounds__(TPB) void mlrl_fused(
        const float* __restrict__ scores,
        const int* __restrict__ idx,
        const int* __restrict__ ndev,
        int total_scores, int total_idx,
        unsigned int* __restrict__ counter,
        float2* __restrict__ partials,
        float* __restrict__ out) {
    const int D = *ndev;                 // 256
    const int B = total_scores / D;      // 2048
    const int K = total_idx / B;         // 8

    float loss = 0.0f, pairs = 0.0f;
    if (K == 8) accum_samples<8>(scores, idx, D, B, K, loss, pairs);
    else        accum_samples<0>(scores, idx, D, B, K, loss, pairs);

    // Block reduction: wave shuffle, then 4 wave-partials via LDS.
    for (int off = 32; off > 0; off >>= 1) {
        loss  += __shfl_down(loss,  off);
        pairs += __shfl_down(pairs, off);
    }
    __shared__ float2 red[TPB / 64];
    __shared__ bool   amLast;
    const int wave = threadIdx.x >> 6;
    const int lane = threadIdx.x & 63;
    if (lane == 0) red[wave] = make_float2(loss, pairs);
    __syncthreads();
    if (threadIdx.x == 0) {
        float2 acc = red[0];
        for (int w = 1; w < TPB / 64; ++w) { acc.x += red[w].x; acc.y += red[w].y; }
        partials[blockIdx.x] = acc;
        __threadfence();                       // release: wbL2 so partial is device-visible
        unsigned int old = atomicAdd(counter, 1u);  // device-scope by default
        amLast = (old == (unsigned int)gridDim.x - 1u);
    }
    __syncthreads();

    if (amLast) {
        __threadfence();                       // acquire: invalidate stale L1/L2 lines
        double l = 0.0, p = 0.0;
        for (int i = threadIdx.x; i < (int)gridDim.x; i += TPB) {
            float2 v = partials[i];
            l += (double)v.x;
            p += (double)v.y;
        }
        for (int off = 32; off > 0; off >>= 1) {
            l += __shfl_down(l, off);
            p += __shfl_down(p, off);
        }
        __shared__ double sl[TPB / 64], sp[TPB / 64];
        if (lane == 0) { sl[wave] = l; sp[wave] = p; }
        __syncthreads();
        if (threadIdx.x == 0) {
            double L = 0.0, P = 0.0;
            for (int w = 0; w < TPB / 64; ++w) { L += sl[w]; P += sp[w]; }
            out[0] = (P > 0.0) ? (float)(L / (P < 1.0 ? 1.0 : P)) : 0.0f;
        }
    }
}

extern "C" void kernel_launch(void* const* d_in, const int* in_sizes, int n_in,
                              void* d_out, int out_size, void* d_ws, size_t ws_size,
                              hipStream_t stream) {
    const float* scores = (const float*)d_in[0];
    const int*   idx    = (const int*)d_in[1];
    const int*   ndev   = (const int*)d_in[2];  // num_developers, device scalar
    float* out = (float*)d_out;

    const int total_scores = in_sizes[0];  // B*D
    const int total_idx    = in_sizes[1];  // B*K

    unsigned int* counter  = (unsigned int*)d_ws;
    float2*       partials = (float2*)((char*)d_ws + 16);

    hipMemsetAsync(d_ws, 0, 4, stream);    // zero the done-counter (graph-legal)

    mlrl_fused<<<NBLK, TPB, 0, stream>>>(scores, idx, ndev,
                                         total_scores, total_idx,
                                         counter, partials, out);
}

// Round 4
// 63.897 us; speedup vs baseline: 1.1674x; 1.1674x over previous
//
#include <hip/hip_runtime.h>

#define TPB 256

// ---- Main kernel: one sample per block (grid-stride for safety). ----
// All idx / positive-score addresses are blockIdx-derived (wave-uniform), so
// the compiler emits scalar s_loads (free broadcast). No LDS, no atomics, no
// __syncthreads in the sample loop. KC>0: compile-time K (bench K=8), fully
// unrolled, index/pos arrays in (s)registers. KC==0: generic fallback.
template <int KC>
__device__ inline void accum_samples(const float* __restrict__ scores,
                                     const int* __restrict__ idx,
                                     int D, int B, int K,
                                     float& loss, float& pairs) {
    for (int b = blockIdx.x; b < B; b += gridDim.x) {
        const int rbase = b * D;
        const int ibase = b * K;

        if (KC > 0) {
            int   ik[KC > 0 ? KC : 1];
            float ps[KC > 0 ? KC : 1];
            int   validmask = 0, P = 0;
#pragma unroll
            for (int k = 0; k < KC; ++k) ik[k] = idx[ibase + k];
#pragma unroll
            for (int k = 0; k < KC; ++k) {
                bool dup = false;
#pragma unroll
                for (int j = 0; j < KC; ++j)
                    if (j < k) dup |= (ik[j] == ik[k]);
                if (!dup) { validmask |= (1 << k); ++P; }
                ps[k] = scores[rbase + ik[k]];   // uniform -> s_load broadcast
            }
            for (int d = threadIdx.x; d < D; d += TPB) {
                const float s = scores[rbase + d] + 1.0f;   // margin folded in
                bool is_pos = false;
#pragma unroll
                for (int k = 0; k < KC; ++k) is_pos |= (ik[k] == d);
                if (!is_pos) {
#pragma unroll
                    for (int k = 0; k < KC; ++k) {
                        if (validmask & (1 << k)) {
                            float v = s - ps[k];
                            loss += (v > 0.0f) ? v : 0.0f;
                        }
                    }
                }
            }
            if (threadIdx.x == 0) pairs += (float)((D - P) * P);
        } else {
            // Generic runtime-K fallback (not hit by the bench shape).
            int P = 0;
            for (int k = 0; k < K; ++k) {
                bool dup = false;
                for (int j = 0; j < k; ++j) dup |= (idx[ibase + j] == idx[ibase + k]);
                if (!dup) ++P;
            }
            for (int d = threadIdx.x; d < D; d += TPB) {
                const float s = scores[rbase + d] + 1.0f;
                bool is_pos = false;
                for (int k = 0; k < K; ++k) is_pos |= (idx[ibase + k] == d);
                if (!is_pos) {
                    for (int k = 0; k < K; ++k) {
                        bool dup = false;
                        for (int j = 0; j < k; ++j) dup |= (idx[ibase + j] == idx[ibase + k]);
                        if (!dup) {
                            float v = s - scores[rbase + idx[ibase + k]];
                            loss += (v > 0.0f) ? v : 0.0f;
                        }
                    }
                }
            }
            if (threadIdx.x == 0) pairs += (float)((D - P) * P);
        }
    }
}

__global__ __launch_bounds__(TPB) void mlrl_main(
        const float* __restrict__ scores,
        const int* __restrict__ idx,
        const int* __restrict__ ndev,
        int total_scores, int total_idx,
        float2* __restrict__ partials) {
    const int D = *ndev;                 // 256
    const int B = total_scores / D;      // 2048
    const int K = total_idx / B;         // 8

    float loss = 0.0f, pairs = 0.0f;
    if (K == 8) accum_samples<8>(scores, idx, D, B, K, loss, pairs);
    else        accum_samples<0>(scores, idx, D, B, K, loss, pairs);

    // Wave shuffle reduction, then 4 wave-partials via LDS.
    for (int off = 32; off > 0; off >>= 1) {
        loss  += __shfl_down(loss,  off);
        pairs += __shfl_down(pairs, off);
    }
    __shared__ float2 red[TPB / 64];
    const int wave = threadIdx.x >> 6;
    const int lane = threadIdx.x & 63;
    if (lane == 0) red[wave] = make_float2(loss, pairs);
    __syncthreads();
    if (threadIdx.x == 0) {
        float2 acc = red[0];
        for (int w = 1; w < TPB / 64; ++w) { acc.x += red[w].x; acc.y += red[w].y; }
        partials[blockIdx.x] = acc;     // plain store -> no ws init needed
    }
}

__global__ __launch_bounds__(TPB) void mlrl_finalize(
        const float2* __restrict__ partials, int n, float* __restrict__ out) {
    double l = 0.0, p = 0.0;
    for (int i = threadIdx.x; i < n; i += blockDim.x) {
        float2 v = partials[i];
        l += (double)v.x;
        p += (double)v.y;
    }
    for (int off = 32; off > 0; off >>= 1) {
        l += __shfl_down(l, off);
        p += __shfl_down(p, off);
    }
    __shared__ double sl[TPB / 64], sp[TPB / 64];
    const int wave = threadIdx.x >> 6;
    const int lane = threadIdx.x & 63;
    if (lane == 0) { sl[wave] = l; sp[wave] = p; }
    __syncthreads();
    if (threadIdx.x == 0) {
        double L = 0.0, P = 0.0;
        for (int w = 0; w < TPB / 64; ++w) { L += sl[w]; P += sp[w]; }
        out[0] = (P > 0.0) ? (float)(L / (P < 1.0 ? 1.0 : P)) : 0.0f;
    }
}

extern "C" void kernel_launch(void* const* d_in, const int* in_sizes, int n_in,
                              void* d_out, int out_size, void* d_ws, size_t ws_size,
                              hipStream_t stream) {
    const float* scores = (const float*)d_in[0];
    const int*   idx    = (const int*)d_in[1];
    const int*   ndev   = (const int*)d_in[2];  // num_developers, device scalar
    float* out = (float*)d_out;

    const int total_scores = in_sizes[0];  // B*D
    const int total_idx    = in_sizes[1];  // B*K

    // Host assumes D=256 for grid sizing (bench shape); in-kernel grid-stride
    // keeps correctness if D differs; all blocks write their partial.
    int nblocks = total_scores / 256;
    if (nblocks < 1) nblocks = 1;
    if ((size_t)nblocks * sizeof(float2) > ws_size)
        nblocks = (int)(ws_size / sizeof(float2));

    float2* partials = (float2*)d_ws;

    mlrl_main<<<nblocks, TPB, 0, stream>>>(scores, idx, ndev,
                                           total_scores, total_idx, partials);
    mlrl_finalize<<<1, TPB, 0, stream>>>(partials, nblocks, out);
}